// Round 21
// baseline (302.423 us; speedup 1.0000x reference)
//
#include <hip/hip_runtime.h>
#include <hip/hip_bf16.h>

#define N_NODES 50000
#define N_EDGES 800000
#define DIM 128
#define N_GRAPHS 32
#define CAP 64     // per-node bucket capacity; deg ~ Poisson(16), P(>=64) ~ 2e-18
#define NPS 128    // nodes per super-bucket
#define NSUP 391   // ceil(50000/128)
#define SBCAP2 2432 // per-sb region capacity; mean 2046, +8.5 sigma
#define EPB 8192   // edges per block in pass A
#define EPT 32     // edges per thread
#define NBLK ((N_EDGES + EPB - 1) / EPB)  // 98
#define AGG_NPB 16 // nodes per k_agg block (4 waves x 4 serial nodes)
#define NSLICE 4   // dim slices (32 dims = 3.2 MB/slice, L2-resident per XCD)

// k_prep block ranges
#define CVT_BLKS (N_NODES * DIM / 4 / 256)        // 6250
#define RPK_BLKS ((6 * 16384 + 255) / 256)        // 384
#define ZRO_BLKS ((N_GRAPHS * DIM + 255) / 256)   // 16 (covers gcnt+gCnt too)
#define PREP_BLKS (CVT_BLKS + RPK_BLKS + ZRO_BLKS)

typedef _Float16 f16;
typedef __attribute__((ext_vector_type(2))) _Float16 f16x2;
typedef __attribute__((ext_vector_type(4))) _Float16 f16x4;
typedef __attribute__((ext_vector_type(8))) _Float16 f16x8;
typedef __attribute__((ext_vector_type(4))) float f32x4;

// ---------------- fused preprocessing: cvt | repack (plain f16) | zero ----------
__global__ __launch_bounds__(256) void k_prep(const float* __restrict__ x,
                                              f16* __restrict__ h16,
                                              const float* __restrict__ W0, const float* __restrict__ W1,
                                              const float* __restrict__ W2, const float* __restrict__ W3,
                                              const float* __restrict__ W4, const float* __restrict__ W5,
                                              f16* __restrict__ pack,
                                              float* __restrict__ pooled,
                                              int* __restrict__ gcnt,
                                              int* __restrict__ gCnt) {
  int blk = blockIdx.x;
  if (blk < CVT_BLKS) {
    int idx = blk * 256 + threadIdx.x;           // one f32x4 per thread
    f32x4 v = *(const f32x4*)(x + idx * 4);
    f16x4 h;
    #pragma unroll
    for (int j = 0; j < 4; ++j) h[j] = (f16)v[j];
    *(f16x4*)(h16 + idx * 4) = h;
    return;
  }
  blk -= CVT_BLKS;
  if (blk < RPK_BLKS) {
    int idx = blk * 256 + threadIdx.x;
    if (idx >= 6 * 16384) return;
    int m = idx >> 14, r = idx & 16383;
    const float* W = m == 0 ? W0 : m == 1 ? W1 : m == 2 ? W2 : m == 3 ? W3 : m == 4 ? W4 : W5;
    int ct = r >> 11, ks = (r >> 9) & 3, l = (r >> 3) & 63, j = r & 7;
    int k = ks * 32 + ((l >> 4) << 3) + j;
    int c = ct * 16 + (l & 15);
    pack[m * 16384 + r] = (f16)W[k * DIM + c];
    return;
  }
  blk -= RPK_BLKS;
  int i = blk * 256 + threadIdx.x;
  if (i < N_GRAPHS * DIM) pooled[i] = 0.f;
  if (i < N_GRAPHS) gcnt[i] = 0;
  if (i < NSUP) gCnt[i] = 0;
}

// ---------------- pass A: LDS-ranked partition into per-sb regions ----------------
__global__ __launch_bounds__(256) void k_part2(const int* __restrict__ src,
                                               const int* __restrict__ dst,
                                               int* __restrict__ gCnt,
                                               unsigned int* __restrict__ sbBuf) {
  __shared__ int hist[NSUP];
  __shared__ int base[NSUP];
  int tid = threadIdx.x;
  int e0 = blockIdx.x * EPB;
  int nE = min(EPB, N_EDGES - e0);
  for (int i = tid; i < NSUP; i += 256) hist[i] = 0;
  __syncthreads();
  unsigned pk[EPT];
  #pragma unroll
  for (int j = 0; j < EPT; ++j) {
    int idx = j * 256 + tid;                 // coalesced
    if (idx < nE) {
      int e = e0 + idx;
      int d = dst[e], s = src[e];
      int sb = d >> 7;                       // NPS = 128
      pk[j] = ((unsigned)sb << 23) | ((unsigned)(d & 127) << 16) | (unsigned)s;
      atomicAdd(&hist[sb], 1);               // LDS atomic, ~21/bin
    } else pk[j] = 0xFFFFFFFFu;
  }
  __syncthreads();
  for (int i = tid; i < NSUP; i += 256) {
    int h = hist[i];
    base[i] = h ? atomicAdd(&gCnt[i], h) : 0; // one global atomic per (block, sb)
    hist[i] = 0;                              // reuse as rank counter
  }
  __syncthreads();
  #pragma unroll
  for (int j = 0; j < EPT; ++j) {
    unsigned p = pk[j];
    if (p != 0xFFFFFFFFu) {
      int sb = p >> 23;
      int slot = base[sb] + atomicAdd(&hist[sb], 1);
      if (slot < SBCAP2)
        sbBuf[(size_t)sb * SBCAP2 + slot] = p & 0x7FFFFFu;  // dl<<16 | src
    }
  }
}

// ---------------- pass B: LDS-bin each super-bucket into per-node buckets ---------
__global__ __launch_bounds__(256) void k_bin(const int* __restrict__ gCnt,
                                             const unsigned int* __restrict__ sbBuf,
                                             int* __restrict__ cnt,
                                             unsigned short* __restrict__ esrc) {
  __shared__ unsigned short buck[NPS * CAP];  // 16 KB
  __shared__ int cl[NPS];
  int sb = blockIdx.x, tid = threadIdx.x;
  for (int i = tid; i < NPS; i += 256) cl[i] = 0;
  __syncthreads();
  int n = min(gCnt[sb], SBCAP2);
  const unsigned int* buf = sbBuf + (size_t)sb * SBCAP2;
  for (int i = tid; i < n; i += 256) {
    unsigned p = buf[i];
    int dl = p >> 16;
    int slot = atomicAdd(&cl[dl], 1);         // LDS atomic
    if (slot < CAP) buck[dl * CAP + slot] = (unsigned short)(p & 0xFFFF);
  }
  __syncthreads();
  size_t basep = (size_t)sb * NPS * CAP;      // == first_node * CAP
  for (int i = tid; i < NPS * CAP; i += 256)  // full-line contiguous writeout
    esrc[basep + i] = buck[i];
  int n0 = sb * NPS;
  for (int d = tid; d < NPS; d += 256) {
    int node = n0 + d;
    if (node < N_NODES) cnt[node] = min(cl[d], CAP);
  }
}

// ---------------- mean aggregation: dim-sliced for per-XCD L2 residency ----------
// slice = blockIdx & 3 (32 dims, 3.2 MB): with round-robin block->XCD dispatch,
// slice s runs on XCDs {s, s+4} only -> each XCD's L2 caches one slice entirely.
__global__ __launch_bounds__(256) void k_agg(const f16* __restrict__ H16,
                                             const int* __restrict__ cnt,
                                             const unsigned short* __restrict__ esrc,
                                             f16* __restrict__ agg16) {
  int slice = blockIdx.x & (NSLICE - 1);
  int group = blockIdx.x >> 2;
  int wid = threadIdx.x >> 6;
  int lane = threadIdx.x & 63;
  int rowslot = lane >> 2;        // 0..15: edge-row slot
  int l4 = lane & 3;              // 16-B chunk within the 64-B slice
  int dimoff = slice * 32 + l4 * 8;
  int node0 = group * AGG_NPB + wid * 4;

  #pragma unroll
  for (int nl = 0; nl < 4; ++nl) {
    int node = node0 + nl;
    int dcnt = cnt[node];
    int b = node * CAP, e = b + dcnt;

    f32x4 a0 = (f32x4){0.f, 0.f, 0.f, 0.f}, a1 = a0;
    for (int i = b + rowslot; i < e; i += 16) {   // 16 edge-rows in flight
      int s = esrc[i];
      f16x8 v = *(const f16x8*)(H16 + (size_t)s * DIM + dimoff);
      #pragma unroll
      for (int j = 0; j < 4; ++j) { a0[j] += (float)v[j]; a1[j] += (float)v[4 + j]; }
    }
    // reduce across the 16 row-slots (lane stride 4)
    #pragma unroll
    for (int j = 0; j < 4; ++j) {
      a0[j] += __shfl_xor(a0[j], 4, 64);  a1[j] += __shfl_xor(a1[j], 4, 64);
      a0[j] += __shfl_xor(a0[j], 8, 64);  a1[j] += __shfl_xor(a1[j], 8, 64);
      a0[j] += __shfl_xor(a0[j], 16, 64); a1[j] += __shfl_xor(a1[j], 16, 64);
      a0[j] += __shfl_xor(a0[j], 32, 64); a1[j] += __shfl_xor(a1[j], 32, 64);
    }
    if (rowslot == 0) {            // lanes 0..3 cover the 32-dim slice
      float inv = 1.0f / (float)max(dcnt, 1);
      f16x8 r;
      #pragma unroll
      for (int j = 0; j < 4; ++j) {
        r[j] = (f16)(a0[j] * inv);
        r[4 + j] = (f16)(a1[j] * inv);
      }
      *(f16x8*)(agg16 + (size_t)node * DIM + dimoff) = r;
    }
  }
}

// ---------------- fused SAGE GEMM, plain-f16 weights, optional pool epilogue -----
template<bool POOL>
__global__ __launch_bounds__(256) void k_gemm(const f16* __restrict__ Agg16,
                                              const f16* __restrict__ Hprev16,
                                              const f16* __restrict__ packWl,
                                              const f16* __restrict__ packWr,
                                              const float* __restrict__ bias,
                                              f16* __restrict__ Hout16,
                                              const int* __restrict__ batch,
                                              float* __restrict__ pooled,
                                              int* __restrict__ gcnt) {
  __shared__ f16 wlds[16384];           // 32 KB: one weight matrix in fragment order
  __shared__ float lpoolw[4][2][DIM];   // 4 KB: per-wave slot-split column partials
  __shared__ int bshared[64];
  int tid = threadIdx.x;
  int wid = tid >> 6, l = tid & 63;
  int row0blk = blockIdx.x * 64;
  int row0 = row0blk + wid * 16;
  int arow = row0 + (l & 15);
  int arowc = min(arow, N_NODES - 1);
  int koff = (l >> 4) << 3;

  if (POOL) {
    if (tid < 64) {
      int r = row0blk + tid;
      bshared[tid] = (r < N_NODES) ? batch[r] : -1;
    }
  }

  f32x4 acc[8];
  #pragma unroll
  for (int ct = 0; ct < 8; ++ct) acc[ct] = (f32x4){0.f, 0.f, 0.f, 0.f};

  #pragma unroll
  for (int mat = 0; mat < 2; ++mat) {
    const f16* A = (mat ? Hprev16 : Agg16) + (size_t)arowc * DIM + koff;
    f16x8 aa[4];
    #pragma unroll
    for (int ks = 0; ks < 4; ++ks) aa[ks] = *(const f16x8*)(A + ks * 32);

    const f16* P = mat ? packWr : packWl;
    if (mat) __syncthreads();   // phase-0 readers done before overwrite
    #pragma unroll
    for (int it = 0; it < 8; ++it) {
      int idx = (it * 256 + tid) * 8;
      *(f16x8*)&wlds[idx] = *(const f16x8*)&P[idx];
    }
    __syncthreads();

    #pragma unroll
    for (int ct = 0; ct < 8; ++ct) {
      #pragma unroll
      for (int ks = 0; ks < 4; ++ks) {
        f16x8 bfrag = *(const f16x8*)&wlds[((ct * 4 + ks) * 64 + l) * 8];
        acc[ct] = __builtin_amdgcn_mfma_f32_16x16x32_f16(aa[ks], bfrag, acc[ct], 0, 0, 0);
      }
    }
  }

  int drowb = row0 + ((l >> 4) << 2);
  int c0 = l & 15;
  int g0 = POOL ? bshared[0] : 0;
  #pragma unroll
  for (int ct = 0; ct < 8; ++ct) {
    int c = ct * 16 + c0;
    float bb = bias[c];
    float ps0 = 0.f, ps1 = 0.f;   // slot-split partials over this thread's 4 rows
    #pragma unroll
    for (int i = 0; i < 4; ++i) {
      int r = drowb + i;
      if (r < N_NODES) {
        float v = acc[ct][i] + bb;
        v = v > 0.f ? v : 0.f;
        if (POOL) {
          if (bshared[r - row0blk] == g0) ps0 += v; else ps1 += v;
        } else {
          Hout16[(size_t)r * DIM + c] = (f16)v;
        }
      }
    }
    if (POOL) {
      ps0 += __shfl_xor(ps0, 16, 64); ps0 += __shfl_xor(ps0, 32, 64);
      ps1 += __shfl_xor(ps1, 16, 64); ps1 += __shfl_xor(ps1, 32, 64);
      if (l < 16) {
        lpoolw[wid][0][c] = ps0;
        lpoolw[wid][1][c] = ps1;
      }
    }
  }

  if (POOL) {
    __syncthreads();
    int rlast = min(row0blk + 63, N_NODES - 1);
    int g1 = bshared[rlast - row0blk];
    int slot = tid >> 7, c = tid & 127;
    float s = lpoolw[0][slot][c] + lpoolw[1][slot][c] +
              lpoolw[2][slot][c] + lpoolw[3][slot][c];
    int g = slot ? g1 : g0;
    atomicAdd(&pooled[g * DIM + c], s);   // slot1 sums are 0 when g1==g0
    if (tid == 0) {
      int c0n = 0, c1n = 0;
      #pragma unroll 8
      for (int i = 0; i < 64; ++i) {
        int b = bshared[i];
        if (b == g0) c0n++;
        else if (b >= 0) c1n++;
      }
      atomicAdd(&gcnt[g0], c0n);
      if (c1n) atomicAdd(&gcnt[g1], c1n);
    }
  }
}

// ---------------- final MLP: one block per graph ----------------
__global__ __launch_bounds__(128) void k_mlp(const float* __restrict__ pooled,
                                             const int* __restrict__ gcnt,
                                             const float* __restrict__ W1,
                                             const float* __restrict__ b1,
                                             const float* __restrict__ W2,
                                             const float* __restrict__ b2,
                                             float* __restrict__ out) {
  int g = blockIdx.x, c = threadIdx.x;
  __shared__ float pn[DIM];
  __shared__ float h1[DIM];
  pn[c] = pooled[g * DIM + c] / (float)max(gcnt[g], 1);
  __syncthreads();
  float s = b1[c];
  #pragma unroll 8
  for (int k = 0; k < DIM; ++k) s += pn[k] * W1[k * DIM + c];
  h1[c] = s > 0.f ? s : 0.f;
  __syncthreads();
  if (c < 8) {
    float s2 = b2[c];
    #pragma unroll 8
    for (int k = 0; k < DIM; ++k) s2 += h1[k] * W2[k * 8 + c];
    out[g * 8 + c] = s2;
  }
}

extern "C" void kernel_launch(void* const* d_in, const int* in_sizes, int n_in,
                              void* d_out, int out_size, void* d_ws, size_t ws_size,
                              hipStream_t stream) {
  const float* x = (const float*)d_in[0];
  const int* ei = (const int*)d_in[1];
  const int* src = ei;
  const int* dst = ei + N_EDGES;
  const int* batch = (const int*)d_in[2];
  const float* Wl1 = (const float*)d_in[3];  const float* bl1 = (const float*)d_in[4];  const float* Wr1 = (const float*)d_in[5];
  const float* Wl2 = (const float*)d_in[6];  const float* bl2 = (const float*)d_in[7];  const float* Wr2 = (const float*)d_in[8];
  const float* Wl3 = (const float*)d_in[9];  const float* bl3 = (const float*)d_in[10]; const float* Wr3 = (const float*)d_in[11];
  const float* W_1 = (const float*)d_in[12]; const float* b_1 = (const float*)d_in[13];
  const float* W_2 = (const float*)d_in[14]; const float* b_2 = (const float*)d_in[15];

  char* ws = (char*)d_ws;
  size_t off = 0;
  auto alloc = [&](size_t bytes) {
    void* p = ws + off;
    off += (bytes + 255) & ~(size_t)255;
    return p;
  };
  f16* agg16 = (f16*)alloc((size_t)N_NODES * DIM * 2);
  f16* h16A  = (f16*)alloc((size_t)N_NODES * DIM * 2);   // x16 / layer-2 out
  f16* h16B  = (f16*)alloc((size_t)N_NODES * DIM * 2);   // layer-1 out
  int* cnt   = (int*)alloc(N_NODES * 4);                 // fully written by k_bin
  unsigned short* esrc = (unsigned short*)alloc((size_t)NSUP * NPS * CAP * 2);
  unsigned int* sbBuf  = (unsigned int*)alloc((size_t)NSUP * SBCAP2 * 4);
  f16* pack  = (f16*)alloc(6 * 16384 * sizeof(f16));
  float* pooled = (float*)alloc(N_GRAPHS * DIM * 4);
  int* gcnt = (int*)alloc(N_GRAPHS * 4);
  int* gCnt = (int*)alloc(NSUP * 4);

  k_prep<<<PREP_BLKS, 256, 0, stream>>>(x, h16A, Wl1, Wr1, Wl2, Wr2, Wl3, Wr3,
                                        pack, pooled, gcnt, gCnt);
  k_part2<<<NBLK, 256, 0, stream>>>(src, dst, gCnt, sbBuf);
  k_bin<<<NSUP, 256, 0, stream>>>(gCnt, sbBuf, cnt, esrc);

  const int gemmBlocks = (N_NODES + 63) / 64;
  const int aggBlocks = (N_NODES / AGG_NPB) * NSLICE;  // 12500: 4 dim-slices x 3125
  // layer 1
  k_agg<<<aggBlocks, 256, 0, stream>>>(h16A, cnt, esrc, agg16);
  k_gemm<false><<<gemmBlocks, 256, 0, stream>>>(agg16, h16A, pack + 0 * 16384, pack + 1 * 16384, bl1, h16B, nullptr, nullptr, nullptr);
  // layer 2
  k_agg<<<aggBlocks, 256, 0, stream>>>(h16B, cnt, esrc, agg16);
  k_gemm<false><<<gemmBlocks, 256, 0, stream>>>(agg16, h16B, pack + 2 * 16384, pack + 3 * 16384, bl2, h16A, nullptr, nullptr, nullptr);
  // layer 3 (pool fused into epilogue; no H store)
  k_agg<<<aggBlocks, 256, 0, stream>>>(h16A, cnt, esrc, agg16);
  k_gemm<true><<<gemmBlocks, 256, 0, stream>>>(agg16, h16A, pack + 4 * 16384, pack + 5 * 16384, bl3, nullptr, batch, pooled, gcnt);

  k_mlp<<<N_GRAPHS, 128, 0, stream>>>(pooled, gcnt, W_1, b_1, W_2, b_2, (float*)d_out);
}

// Round 22
// 205.069 us; speedup vs baseline: 1.4747x; 1.4747x over previous
//
#include <hip/hip_runtime.h>
#include <hip/hip_bf16.h>

#define N_NODES 50000
#define N_EDGES 800000
#define DIM 128
#define N_GRAPHS 32
#define CAP 64     // per-node bucket capacity; deg ~ Poisson(16), P(>=64) ~ 2e-18
#define NPS 128    // nodes per super-bucket
#define NSUP 391   // ceil(50000/128)
#define SBCAP2 2432 // per-sb region capacity; mean 2046, +8.5 sigma
#define EPB 8192   // edges per block in pass A
#define EPT 32     // edges per thread
#define NBLK ((N_EDGES + EPB - 1) / EPB)  // 98
#define AGG_NPB 16 // nodes per k_agg block (4 waves x 4 serial nodes)

// k_prep block ranges
#define CVT_BLKS (N_NODES * DIM / 4 / 256)        // 6250
#define RPK_BLKS ((6 * 16384 + 255) / 256)        // 384
#define ZRO_BLKS ((N_GRAPHS * DIM + 255) / 256)   // 16 (covers gcnt+gCnt too)
#define PREP_BLKS (CVT_BLKS + RPK_BLKS + ZRO_BLKS)

typedef _Float16 f16;
typedef __attribute__((ext_vector_type(2))) _Float16 f16x2;
typedef __attribute__((ext_vector_type(4))) _Float16 f16x4;
typedef __attribute__((ext_vector_type(8))) _Float16 f16x8;
typedef __attribute__((ext_vector_type(4))) float f32x4;

// ---------------- fused preprocessing: cvt | repack (plain f16) | zero ----------
__global__ __launch_bounds__(256) void k_prep(const float* __restrict__ x,
                                              f16* __restrict__ h16,
                                              const float* __restrict__ W0, const float* __restrict__ W1,
                                              const float* __restrict__ W2, const float* __restrict__ W3,
                                              const float* __restrict__ W4, const float* __restrict__ W5,
                                              f16* __restrict__ pack,
                                              float* __restrict__ pooled,
                                              int* __restrict__ gcnt,
                                              int* __restrict__ gCnt) {
  int blk = blockIdx.x;
  if (blk < CVT_BLKS) {
    int idx = blk * 256 + threadIdx.x;           // one f32x4 per thread
    f32x4 v = *(const f32x4*)(x + idx * 4);
    f16x4 h;
    #pragma unroll
    for (int j = 0; j < 4; ++j) h[j] = (f16)v[j];
    *(f16x4*)(h16 + idx * 4) = h;
    return;
  }
  blk -= CVT_BLKS;
  if (blk < RPK_BLKS) {
    int idx = blk * 256 + threadIdx.x;
    if (idx >= 6 * 16384) return;
    int m = idx >> 14, r = idx & 16383;
    const float* W = m == 0 ? W0 : m == 1 ? W1 : m == 2 ? W2 : m == 3 ? W3 : m == 4 ? W4 : W5;
    int ct = r >> 11, ks = (r >> 9) & 3, l = (r >> 3) & 63, j = r & 7;
    int k = ks * 32 + ((l >> 4) << 3) + j;
    int c = ct * 16 + (l & 15);
    pack[m * 16384 + r] = (f16)W[k * DIM + c];
    return;
  }
  blk -= RPK_BLKS;
  int i = blk * 256 + threadIdx.x;
  if (i < N_GRAPHS * DIM) pooled[i] = 0.f;
  if (i < N_GRAPHS) gcnt[i] = 0;
  if (i < NSUP) gCnt[i] = 0;
}

// ---------------- pass A: LDS-ranked partition into per-sb regions ----------------
__global__ __launch_bounds__(256) void k_part2(const int* __restrict__ src,
                                               const int* __restrict__ dst,
                                               int* __restrict__ gCnt,
                                               unsigned int* __restrict__ sbBuf) {
  __shared__ int hist[NSUP];
  __shared__ int base[NSUP];
  int tid = threadIdx.x;
  int e0 = blockIdx.x * EPB;
  int nE = min(EPB, N_EDGES - e0);
  for (int i = tid; i < NSUP; i += 256) hist[i] = 0;
  __syncthreads();
  unsigned pk[EPT];
  #pragma unroll
  for (int j = 0; j < EPT; ++j) {
    int idx = j * 256 + tid;                 // coalesced
    if (idx < nE) {
      int e = e0 + idx;
      int d = dst[e], s = src[e];
      int sb = d >> 7;                       // NPS = 128
      pk[j] = ((unsigned)sb << 23) | ((unsigned)(d & 127) << 16) | (unsigned)s;
      atomicAdd(&hist[sb], 1);               // LDS atomic, ~21/bin
    } else pk[j] = 0xFFFFFFFFu;
  }
  __syncthreads();
  for (int i = tid; i < NSUP; i += 256) {
    int h = hist[i];
    base[i] = h ? atomicAdd(&gCnt[i], h) : 0; // one global atomic per (block, sb)
    hist[i] = 0;                              // reuse as rank counter
  }
  __syncthreads();
  #pragma unroll
  for (int j = 0; j < EPT; ++j) {
    unsigned p = pk[j];
    if (p != 0xFFFFFFFFu) {
      int sb = p >> 23;
      int slot = base[sb] + atomicAdd(&hist[sb], 1);
      if (slot < SBCAP2)
        sbBuf[(size_t)sb * SBCAP2 + slot] = p & 0x7FFFFFu;  // dl<<16 | src
    }
  }
}

// ---------------- pass B: LDS-bin each super-bucket into per-node buckets ---------
__global__ __launch_bounds__(256) void k_bin(const int* __restrict__ gCnt,
                                             const unsigned int* __restrict__ sbBuf,
                                             int* __restrict__ cnt,
                                             unsigned short* __restrict__ esrc) {
  __shared__ unsigned short buck[NPS * CAP];  // 16 KB
  __shared__ int cl[NPS];
  int sb = blockIdx.x, tid = threadIdx.x;
  for (int i = tid; i < NPS; i += 256) cl[i] = 0;
  __syncthreads();
  int n = min(gCnt[sb], SBCAP2);
  const unsigned int* buf = sbBuf + (size_t)sb * SBCAP2;
  for (int i = tid; i < n; i += 256) {
    unsigned p = buf[i];
    int dl = p >> 16;
    int slot = atomicAdd(&cl[dl], 1);         // LDS atomic
    if (slot < CAP) buck[dl * CAP + slot] = (unsigned short)(p & 0xFFFF);
  }
  __syncthreads();
  size_t basep = (size_t)sb * NPS * CAP;      // == first_node * CAP
  for (int i = tid; i < NPS * CAP; i += 256)  // full-line contiguous writeout
    esrc[basep + i] = buck[i];
  int n0 = sb * NPS;
  for (int d = tid; d < NPS; d += 256) {
    int node = n0 + d;
    if (node < N_NODES) cnt[node] = min(cl[d], CAP);
  }
}

// ---------------- mean aggregation: 4 serial nodes per wave ----------------
__global__ __launch_bounds__(256) void k_agg(const f16* __restrict__ H16,
                                             const int* __restrict__ cnt,
                                             const unsigned short* __restrict__ esrc,
                                             f16* __restrict__ agg16) {
  int wid = threadIdx.x >> 6;
  int lane = threadIdx.x & 63;
  int l16 = lane & 15;       // dims l16*8 .. l16*8+7 (16 B)
  int sg = lane >> 4;        // slot group 0..3
  int node0 = blockIdx.x * AGG_NPB + wid * 4;

  #pragma unroll
  for (int nl = 0; nl < 4; ++nl) {
    int node = node0 + nl;
    int dcnt = cnt[node];
    int b = node * CAP, e = b + dcnt;

    f32x4 aA0 = (f32x4){0.f,0.f,0.f,0.f}, aA1 = aA0, aB0 = aA0, aB1 = aA0,
          aC0 = aA0, aC1 = aA0, aD0 = aA0, aD1 = aA0;
    int i = b + sg;
    for (; i + 12 < e; i += 16) {     // 16 edge-rows in flight per wave
      int s0 = esrc[i], s1 = esrc[i + 4], s2 = esrc[i + 8], s3 = esrc[i + 12];
      f16x8 v0 = *(const f16x8*)(H16 + (size_t)s0 * DIM + l16 * 8);
      f16x8 v1 = *(const f16x8*)(H16 + (size_t)s1 * DIM + l16 * 8);
      f16x8 v2 = *(const f16x8*)(H16 + (size_t)s2 * DIM + l16 * 8);
      f16x8 v3 = *(const f16x8*)(H16 + (size_t)s3 * DIM + l16 * 8);
      #pragma unroll
      for (int j = 0; j < 4; ++j) {
        aA0[j] += (float)v0[j]; aA1[j] += (float)v0[4 + j];
        aB0[j] += (float)v1[j]; aB1[j] += (float)v1[4 + j];
        aC0[j] += (float)v2[j]; aC1[j] += (float)v2[4 + j];
        aD0[j] += (float)v3[j]; aD1[j] += (float)v3[4 + j];
      }
    }
    for (; i < e; i += 4) {
      int s = esrc[i];
      f16x8 v = *(const f16x8*)(H16 + (size_t)s * DIM + l16 * 8);
      #pragma unroll
      for (int j = 0; j < 4; ++j) { aA0[j] += (float)v[j]; aA1[j] += (float)v[4 + j]; }
    }
    #pragma unroll
    for (int j = 0; j < 4; ++j) {
      aA0[j] = (aA0[j] + aB0[j]) + (aC0[j] + aD0[j]);
      aA1[j] = (aA1[j] + aB1[j]) + (aC1[j] + aD1[j]);
    }
    #pragma unroll
    for (int j = 0; j < 4; ++j) {
      aA0[j] += __shfl_xor(aA0[j], 16, 64);
      aA1[j] += __shfl_xor(aA1[j], 16, 64);
      aA0[j] += __shfl_xor(aA0[j], 32, 64);
      aA1[j] += __shfl_xor(aA1[j], 32, 64);
    }
    if (lane < 16) {
      float inv = 1.0f / (float)max(dcnt, 1);
      f16x8 r;
      #pragma unroll
      for (int j = 0; j < 4; ++j) {
        r[j] = (f16)(aA0[j] * inv);
        r[4 + j] = (f16)(aA1[j] * inv);
      }
      *(f16x8*)(agg16 + (size_t)node * DIM + l16 * 8) = r;
    }
  }
}

// ---------------- fused SAGE GEMM, plain-f16 weights, optional pool epilogue -----
template<bool POOL>
__global__ __launch_bounds__(256) void k_gemm(const f16* __restrict__ Agg16,
                                              const f16* __restrict__ Hprev16,
                                              const f16* __restrict__ packWl,
                                              const f16* __restrict__ packWr,
                                              const float* __restrict__ bias,
                                              f16* __restrict__ Hout16,
                                              const int* __restrict__ batch,
                                              float* __restrict__ pooled,
                                              int* __restrict__ gcnt) {
  __shared__ f16 wlds[16384];           // 32 KB: one weight matrix in fragment order
  __shared__ float lpoolw[4][2][DIM];   // 4 KB: per-wave slot-split column partials
  __shared__ int bshared[64];
  int tid = threadIdx.x;
  int wid = tid >> 6, l = tid & 63;
  int row0blk = blockIdx.x * 64;
  int row0 = row0blk + wid * 16;
  int arow = row0 + (l & 15);
  int arowc = min(arow, N_NODES - 1);
  int koff = (l >> 4) << 3;

  if (POOL) {
    if (tid < 64) {
      int r = row0blk + tid;
      bshared[tid] = (r < N_NODES) ? batch[r] : -1;
    }
  }

  f32x4 acc[8];
  #pragma unroll
  for (int ct = 0; ct < 8; ++ct) acc[ct] = (f32x4){0.f, 0.f, 0.f, 0.f};

  #pragma unroll
  for (int mat = 0; mat < 2; ++mat) {
    const f16* A = (mat ? Hprev16 : Agg16) + (size_t)arowc * DIM + koff;
    f16x8 aa[4];
    #pragma unroll
    for (int ks = 0; ks < 4; ++ks) aa[ks] = *(const f16x8*)(A + ks * 32);

    const f16* P = mat ? packWr : packWl;
    if (mat) __syncthreads();   // phase-0 readers done before overwrite
    #pragma unroll
    for (int it = 0; it < 8; ++it) {
      int idx = (it * 256 + tid) * 8;
      *(f16x8*)&wlds[idx] = *(const f16x8*)&P[idx];
    }
    __syncthreads();

    #pragma unroll
    for (int ct = 0; ct < 8; ++ct) {
      #pragma unroll
      for (int ks = 0; ks < 4; ++ks) {
        f16x8 bfrag = *(const f16x8*)&wlds[((ct * 4 + ks) * 64 + l) * 8];
        acc[ct] = __builtin_amdgcn_mfma_f32_16x16x32_f16(aa[ks], bfrag, acc[ct], 0, 0, 0);
      }
    }
  }

  int drowb = row0 + ((l >> 4) << 2);
  int c0 = l & 15;
  int g0 = POOL ? bshared[0] : 0;
  #pragma unroll
  for (int ct = 0; ct < 8; ++ct) {
    int c = ct * 16 + c0;
    float bb = bias[c];
    float ps0 = 0.f, ps1 = 0.f;   // slot-split partials over this thread's 4 rows
    #pragma unroll
    for (int i = 0; i < 4; ++i) {
      int r = drowb + i;
      if (r < N_NODES) {
        float v = acc[ct][i] + bb;
        v = v > 0.f ? v : 0.f;
        if (POOL) {
          if (bshared[r - row0blk] == g0) ps0 += v; else ps1 += v;
        } else {
          Hout16[(size_t)r * DIM + c] = (f16)v;
        }
      }
    }
    if (POOL) {
      ps0 += __shfl_xor(ps0, 16, 64); ps0 += __shfl_xor(ps0, 32, 64);
      ps1 += __shfl_xor(ps1, 16, 64); ps1 += __shfl_xor(ps1, 32, 64);
      if (l < 16) {
        lpoolw[wid][0][c] = ps0;
        lpoolw[wid][1][c] = ps1;
      }
    }
  }

  if (POOL) {
    __syncthreads();
    int rlast = min(row0blk + 63, N_NODES - 1);
    int g1 = bshared[rlast - row0blk];
    int slot = tid >> 7, c = tid & 127;
    float s = lpoolw[0][slot][c] + lpoolw[1][slot][c] +
              lpoolw[2][slot][c] + lpoolw[3][slot][c];
    int g = slot ? g1 : g0;
    atomicAdd(&pooled[g * DIM + c], s);   // slot1 sums are 0 when g1==g0
    if (tid == 0) {
      int c0n = 0, c1n = 0;
      #pragma unroll 8
      for (int i = 0; i < 64; ++i) {
        int b = bshared[i];
        if (b == g0) c0n++;
        else if (b >= 0) c1n++;
      }
      atomicAdd(&gcnt[g0], c0n);
      if (c1n) atomicAdd(&gcnt[g1], c1n);
    }
  }
}

// ---------------- final MLP: one block per graph ----------------
__global__ __launch_bounds__(128) void k_mlp(const float* __restrict__ pooled,
                                             const int* __restrict__ gcnt,
                                             const float* __restrict__ W1,
                                             const float* __restrict__ b1,
                                             const float* __restrict__ W2,
                                             const float* __restrict__ b2,
                                             float* __restrict__ out) {
  int g = blockIdx.x, c = threadIdx.x;
  __shared__ float pn[DIM];
  __shared__ float h1[DIM];
  pn[c] = pooled[g * DIM + c] / (float)max(gcnt[g], 1);
  __syncthreads();
  float s = b1[c];
  #pragma unroll 8
  for (int k = 0; k < DIM; ++k) s += pn[k] * W1[k * DIM + c];
  h1[c] = s > 0.f ? s : 0.f;
  __syncthreads();
  if (c < 8) {
    float s2 = b2[c];
    #pragma unroll 8
    for (int k = 0; k < DIM; ++k) s2 += h1[k] * W2[k * 8 + c];
    out[g * 8 + c] = s2;
  }
}

extern "C" void kernel_launch(void* const* d_in, const int* in_sizes, int n_in,
                              void* d_out, int out_size, void* d_ws, size_t ws_size,
                              hipStream_t stream) {
  const float* x = (const float*)d_in[0];
  const int* ei = (const int*)d_in[1];
  const int* src = ei;
  const int* dst = ei + N_EDGES;
  const int* batch = (const int*)d_in[2];
  const float* Wl1 = (const float*)d_in[3];  const float* bl1 = (const float*)d_in[4];  const float* Wr1 = (const float*)d_in[5];
  const float* Wl2 = (const float*)d_in[6];  const float* bl2 = (const float*)d_in[7];  const float* Wr2 = (const float*)d_in[8];
  const float* Wl3 = (const float*)d_in[9];  const float* bl3 = (const float*)d_in[10]; const float* Wr3 = (const float*)d_in[11];
  const float* W_1 = (const float*)d_in[12]; const float* b_1 = (const float*)d_in[13];
  const float* W_2 = (const float*)d_in[14]; const float* b_2 = (const float*)d_in[15];

  char* ws = (char*)d_ws;
  size_t off = 0;
  auto alloc = [&](size_t bytes) {
    void* p = ws + off;
    off += (bytes + 255) & ~(size_t)255;
    return p;
  };
  f16* agg16 = (f16*)alloc((size_t)N_NODES * DIM * 2);
  f16* h16A  = (f16*)alloc((size_t)N_NODES * DIM * 2);   // x16 / layer-2 out
  f16* h16B  = (f16*)alloc((size_t)N_NODES * DIM * 2);   // layer-1 out
  int* cnt   = (int*)alloc(N_NODES * 4);                 // fully written by k_bin
  unsigned short* esrc = (unsigned short*)alloc((size_t)NSUP * NPS * CAP * 2);
  unsigned int* sbBuf  = (unsigned int*)alloc((size_t)NSUP * SBCAP2 * 4);
  f16* pack  = (f16*)alloc(6 * 16384 * sizeof(f16));
  float* pooled = (float*)alloc(N_GRAPHS * DIM * 4);
  int* gcnt = (int*)alloc(N_GRAPHS * 4);
  int* gCnt = (int*)alloc(NSUP * 4);

  k_prep<<<PREP_BLKS, 256, 0, stream>>>(x, h16A, Wl1, Wr1, Wl2, Wr2, Wl3, Wr3,
                                        pack, pooled, gcnt, gCnt);
  k_part2<<<NBLK, 256, 0, stream>>>(src, dst, gCnt, sbBuf);
  k_bin<<<NSUP, 256, 0, stream>>>(gCnt, sbBuf, cnt, esrc);

  const int gemmBlocks = (N_NODES + 63) / 64;
  const int aggBlocks = N_NODES / AGG_NPB;  // 3125 blocks, 4 nodes per wave
  // layer 1
  k_agg<<<aggBlocks, 256, 0, stream>>>(h16A, cnt, esrc, agg16);
  k_gemm<false><<<gemmBlocks, 256, 0, stream>>>(agg16, h16A, pack + 0 * 16384, pack + 1 * 16384, bl1, h16B, nullptr, nullptr, nullptr);
  // layer 2
  k_agg<<<aggBlocks, 256, 0, stream>>>(h16B, cnt, esrc, agg16);
  k_gemm<false><<<gemmBlocks, 256, 0, stream>>>(agg16, h16B, pack + 2 * 16384, pack + 3 * 16384, bl2, h16A, nullptr, nullptr, nullptr);
  // layer 3 (pool fused into epilogue; no H store)
  k_agg<<<aggBlocks, 256, 0, stream>>>(h16A, cnt, esrc, agg16);
  k_gemm<true><<<gemmBlocks, 256, 0, stream>>>(agg16, h16A, pack + 4 * 16384, pack + 5 * 16384, bl3, nullptr, batch, pooled, gcnt);

  k_mlp<<<N_GRAPHS, 128, 0, stream>>>(pooled, gcnt, W_1, b_1, W_2, b_2, (float*)d_out);
}